// Round 6
// baseline (338.455 us; speedup 1.0000x reference)
//
#include <hip/hip_runtime.h>

typedef _Float16 half8_t __attribute__((ext_vector_type(8)));
typedef _Float16 half4_t __attribute__((ext_vector_type(4)));
typedef float    float4_t __attribute__((ext_vector_type(4)));

#define DIM 768

// async global->LDS, 16B per lane; LDS dest is wave-uniform base + lane*16
#define GLOAD16(g, l) __builtin_amdgcn_global_load_lds(                        \
    (const __attribute__((address_space(1))) void*)(g),                        \
    (__attribute__((address_space(3))) void*)(l), 16, 0, 0)

#define MFMA16(a, b, c) __builtin_amdgcn_mfma_f32_16x16x32_f16((a), (b), (c), 0, 0, 0)

// ---------------------------------------------------------------------------
// weight cast (tiny: 4 x 768x768)
// ---------------------------------------------------------------------------
__global__ __launch_bounds__(256) void cast4_f32_f16(
    const float* __restrict__ s0, const float* __restrict__ s1,
    const float* __restrict__ s2, const float* __restrict__ s3,
    _Float16* __restrict__ d0, _Float16* __restrict__ d1,
    _Float16* __restrict__ d2, _Float16* __restrict__ d3)
{
    const float* s; _Float16* d;
    switch (blockIdx.y) {
        case 0: s = s0; d = d0; break;
        case 1: s = s1; d = d1; break;
        case 2: s = s2; d = d2; break;
        default: s = s3; d = d3; break;
    }
    int i = blockIdx.x * 256 + threadIdx.x;
    float4_t f0 = *(const float4_t*)&s[(size_t)i * 8];
    float4_t f1 = *(const float4_t*)&s[(size_t)i * 8 + 4];
    half8_t h;
    #pragma unroll
    for (int e = 0; e < 4; ++e) { h[e] = (_Float16)f0[e]; h[e + 4] = (_Float16)f1[e]; }
    *(half8_t*)&d[(size_t)i * 8] = h;
}

// ---------------------------------------------------------------------------
// GEMM core: out tile 256x128, BK=64, 12 K-tiles, 512 thr = 8 waves (2M x 4N),
// per-wave C 128x32 (acc[8][2]).
// LDS: 3 slots x 48KB (A 32KB = 32 chunks, B 16KB = 16 chunks).
// Chunk = 1KB = 16 rows x 32 halves, granule-transposed: 16B-slot g holds
// (row = g&15, koct = g>>4) -> frag read = chunk_base + lane*16B, contiguous,
// conflict-free, and exactly the MFMA fragment layout (proven r5).
// Pipeline (per tile t; slots s=t%3, s1, s2):
//   phase0: ds_read bf + af[0..3] | issue A(t+2) (+B(t+2) gload_lds -> s2)
//           | barrier | lgkm(0) | 16 MFMA | barrier
//   phase1: ds_read af[4..7] | [AF32: vmcnt(10) => A(t+1)&B(t+1) landed;
//           cvt+ds_write A(t+1) -> s1] | barrier | lgkm(0) | 16 MFMA |
//           [F16: vmcnt(6) counted] | barrier
// AF32 path reg-stages fp32 A (T14): loads 2 tiles ahead, writes 1 ahead;
// no separate cast pass needed. F16 path = 6 gload_lds/tile (r4 cadence).
// ---------------------------------------------------------------------------
template<bool AF32>
__device__ __forceinline__ void gemm_core(const void* __restrict__ Av,
                                          const _Float16* __restrict__ W,
                                          int row0, int col0,
                                          _Float16* lds, float4_t acc[8][2])
{
    const int tid  = threadIdx.x;
    const int wid  = tid >> 6, lane = tid & 63;
    const int wr   = wid >> 2, wc = wid & 3;

    // B staging (fp16 weights): wave w stages B rowgroup w (2 chunks)
    const _Float16* Bst = W + (size_t)(col0 + wid * 16 + (lane & 15)) * DIM
                            + (lane >> 4) * 8;

    // frag read offsets (halves)
    const int aoffs = (wr * 8) * 1024 + lane * 8;
    const int boffs = 16384 + (wc * 2) * 1024 + lane * 8;

    // A staging
    const _Float16* Ah = nullptr;
    const float*    Af = nullptr;
    int awr = 0;
    if constexpr (AF32) {
        const int rg = 2 * wid + (lane >> 5);   // rowgroup 0..15
        const int j  = lane & 31;
        const int row = j & 15, q = j >> 4;     // q = khalf
        Af  = (const float*)Av + (size_t)(row0 + rg * 16 + row) * DIM + q * 32;
        awr = (rg * 2 + q) * 512 + row * 8;     // + p*128, p = koct
    } else {
        Ah = (const _Float16*)Av + (size_t)(row0 + 2 * wid * 16 + (lane & 15)) * DIM
                                 + (lane >> 4) * 8;
    }

#define B_STAGE(t, s) do {                                                     \
        GLOAD16(Bst + (t) * 64,      &lds[(s) * 24576 + 16384 + (2*wid  ) * 512]); \
        GLOAD16(Bst + (t) * 64 + 32, &lds[(s) * 24576 + 16384 + (2*wid+1) * 512]); \
    } while (0)

#define AH_STAGE(t, s) do {                                                    \
        GLOAD16(Ah + (t)*64,              &lds[(s)*24576 + (4*wid  )*512]);    \
        GLOAD16(Ah + (t)*64 + 32,         &lds[(s)*24576 + (4*wid+1)*512]);    \
        GLOAD16(Ah + (t)*64 + 16*DIM,     &lds[(s)*24576 + (4*wid+2)*512]);    \
        GLOAD16(Ah + (t)*64 + 16*DIM+32,  &lds[(s)*24576 + (4*wid+3)*512]);    \
    } while (0)

#define AF_ISSUE(t, R) do { _Pragma("unroll")                                  \
        for (int i = 0; i < 8; ++i)                                            \
            R[i] = *(const float4_t*)(Af + (t) * 64 + i * 4);                  \
    } while (0)

#define AF_WRITE(s1w, R) do {                                                  \
        _Float16* dst = &lds[(s1w) * 24576 + awr];                             \
        _Pragma("unroll") for (int p = 0; p < 4; ++p) {                        \
            half8_t h;                                                         \
            _Pragma("unroll") for (int e = 0; e < 4; ++e) {                    \
                h[e] = (_Float16)R[2*p][e]; h[4+e] = (_Float16)R[2*p+1][e]; }  \
            *(half8_t*)&dst[p * 128] = h; }                                    \
    } while (0)

#define READ_BF(s) do {                                                        \
        bf[0][0] = *(const half8_t*)&lds[(s)*24576 + boffs];                   \
        bf[0][1] = *(const half8_t*)&lds[(s)*24576 + boffs + 512];             \
        bf[1][0] = *(const half8_t*)&lds[(s)*24576 + boffs + 1024];            \
        bf[1][1] = *(const half8_t*)&lds[(s)*24576 + boffs + 1536];            \
    } while (0)

#define READ_AFR(af, s, mb) do { _Pragma("unroll")                             \
        for (int i = 0; i < 4; ++i) {                                          \
            af[i][0] = *(const half8_t*)&lds[(s)*24576 + aoffs + ((mb)+i)*1024];       \
            af[i][1] = *(const half8_t*)&lds[(s)*24576 + aoffs + ((mb)+i)*1024 + 512]; \
        } } while (0)

#define MMA4(base, af) do {                                                    \
        asm volatile("s_waitcnt lgkmcnt(0)" ::: "memory");                     \
        __builtin_amdgcn_sched_barrier(0);                                     \
        __builtin_amdgcn_s_setprio(1);                                         \
        _Pragma("unroll") for (int i = 0; i < 4; ++i)                          \
            _Pragma("unroll") for (int n2 = 0; n2 < 2; ++n2) {                 \
                acc[(base)+i][n2] = MFMA16(af[i][0], bf[n2][0], acc[(base)+i][n2]); \
                acc[(base)+i][n2] = MFMA16(af[i][1], bf[n2][1], acc[(base)+i][n2]); \
            }                                                                  \
        __builtin_amdgcn_s_setprio(0);                                         \
        __builtin_amdgcn_sched_barrier(0);                                     \
    } while (0)

    if constexpr (AF32) {
        float4_t Ra[8], Rb[8];
        // ---- prologue: A(0)->Ra, B(0)->s0; A(1)->Rb, B(1)->s1 ----
        AF_ISSUE(0, Ra); B_STAGE(0, 0);
        __builtin_amdgcn_sched_barrier(0);
        AF_ISSUE(1, Rb); B_STAGE(1, 1);
        __builtin_amdgcn_sched_barrier(0);
        asm volatile("s_waitcnt vmcnt(10)" ::: "memory");   // A(0),B(0) landed
        AF_WRITE(0, Ra);
        asm volatile("s_waitcnt lgkmcnt(0)" ::: "memory");
        __builtin_amdgcn_sched_barrier(0);
        __builtin_amdgcn_s_barrier();

#define TILE_F32(t, Ri, Rw) do {                                               \
        const int s = (t) % 3, s1 = ((t)+1) % 3, s2 = ((t)+2) % 3;             \
        __builtin_amdgcn_sched_barrier(0);                                     \
        half8_t bf[2][2];                                                      \
        READ_BF(s);                                                            \
        { half8_t af[4][2]; READ_AFR(af, s, 0);                                \
          AF_ISSUE((t)+2, Ri); B_STAGE((t)+2, s2);                             \
          __builtin_amdgcn_s_barrier();                                        \
          MMA4(0, af);                                                         \
          __builtin_amdgcn_s_barrier(); }                                      \
        { half8_t af[4][2]; READ_AFR(af, s, 4);                                \
          asm volatile("s_waitcnt vmcnt(10)" ::: "memory");                    \
          AF_WRITE(s1, Rw);                                                    \
          __builtin_amdgcn_s_barrier();                                        \
          MMA4(4, af);                                                         \
          __builtin_amdgcn_s_barrier(); }                                      \
    } while (0)

        #pragma unroll
        for (int t = 0; t < 10; t += 2) {
            TILE_F32(t,     Ra, Rb);   // issue A(t+2)->Ra, write A(t+1) from Rb
            TILE_F32(t + 1, Rb, Ra);
        }
        // ---- t = 10: no issue; write A(11) from Rb (s=1, s1=2) ----
        {
            __builtin_amdgcn_sched_barrier(0);
            half8_t bf[2][2];
            READ_BF(1);
            { half8_t af[4][2]; READ_AFR(af, 1, 0);
              __builtin_amdgcn_s_barrier();
              MMA4(0, af);
              __builtin_amdgcn_s_barrier(); }
            { half8_t af[4][2]; READ_AFR(af, 1, 4);
              asm volatile("s_waitcnt vmcnt(0)" ::: "memory");   // A(11),B(11)
              AF_WRITE(2, Rb);
              __builtin_amdgcn_s_barrier();
              MMA4(4, af);
              __builtin_amdgcn_s_barrier(); }
        }
        // ---- t = 11 (s=2) ----
        {
            __builtin_amdgcn_sched_barrier(0);
            half8_t bf[2][2];
            READ_BF(2);
            { half8_t af[4][2]; READ_AFR(af, 2, 0);
              __builtin_amdgcn_s_barrier();
              MMA4(0, af);
              __builtin_amdgcn_s_barrier(); }
            { half8_t af[4][2]; READ_AFR(af, 2, 4);
              __builtin_amdgcn_s_barrier();
              MMA4(4, af); }
        }
#undef TILE_F32
    } else {
        // ---- fp16-A path: 6 gload_lds per tile, counted vmcnt(6) ----
        AH_STAGE(0, 0); B_STAGE(0, 0);
        __builtin_amdgcn_sched_barrier(0);
        AH_STAGE(1, 1); B_STAGE(1, 1);
        __builtin_amdgcn_sched_barrier(0);
        asm volatile("s_waitcnt vmcnt(6)" ::: "memory");   // tile0 landed
        __builtin_amdgcn_s_barrier();

#define TILE_H16(t) do {                                                       \
        const int s = (t) % 3, s2 = ((t)+2) % 3;                               \
        __builtin_amdgcn_sched_barrier(0);                                     \
        half8_t bf[2][2];                                                      \
        READ_BF(s);                                                            \
        { half8_t af[4][2]; READ_AFR(af, s, 0);                                \
          AH_STAGE((t)+2, s2); B_STAGE((t)+2, s2);                             \
          __builtin_amdgcn_s_barrier();                                        \
          MMA4(0, af);                                                         \
          __builtin_amdgcn_s_barrier(); }                                      \
        { half8_t af[4][2]; READ_AFR(af, s, 4);                                \
          __builtin_amdgcn_s_barrier();                                        \
          MMA4(4, af);                                                         \
          asm volatile("s_waitcnt vmcnt(6)" ::: "memory");                     \
          __builtin_amdgcn_s_barrier(); }                                      \
    } while (0)

        #pragma unroll
        for (int t = 0; t < 10; ++t) TILE_H16(t);
        // ---- t = 10: no issue; drain tile-11 loads ----
        {
            __builtin_amdgcn_sched_barrier(0);
            half8_t bf[2][2];
            READ_BF(1);
            { half8_t af[4][2]; READ_AFR(af, 1, 0);
              __builtin_amdgcn_s_barrier();
              MMA4(0, af);
              __builtin_amdgcn_s_barrier(); }
            { half8_t af[4][2]; READ_AFR(af, 1, 4);
              __builtin_amdgcn_s_barrier();
              MMA4(4, af);
              asm volatile("s_waitcnt vmcnt(0)" ::: "memory");
              __builtin_amdgcn_s_barrier(); }
        }
        // ---- t = 11 ----
        {
            __builtin_amdgcn_sched_barrier(0);
            half8_t bf[2][2];
            READ_BF(2);
            { half8_t af[4][2]; READ_AFR(af, 2, 0);
              __builtin_amdgcn_s_barrier();
              MMA4(0, af);
              __builtin_amdgcn_s_barrier(); }
            { half8_t af[4][2]; READ_AFR(af, 2, 4);
              __builtin_amdgcn_s_barrier();
              MMA4(4, af); }
        }
#undef TILE_H16
    }
#undef B_STAGE
#undef AH_STAGE
#undef AF_ISSUE
#undef AF_WRITE
#undef READ_BF
#undef READ_AFR
#undef MMA4
}

// ---------------------------------------------------------------------------
// Fused q/k/v projection, fp32 activations in (cast fused into staging).
//   bid <  768 : q = elu1(xq @ Wq.T)   (128 row-blocks x 6 cols)
//   768..959   : k = elu1(xkv @ Wk.T)  ( 32 row-blocks x 6)
//   960..1151  : v =      xkv @ Wv.T
// ---------------------------------------------------------------------------
__global__ __launch_bounds__(512) void proj_qkv(
    const float* __restrict__ xq, const float* __restrict__ xkv,
    const _Float16* __restrict__ Wq16, const _Float16* __restrict__ Wk16,
    const _Float16* __restrict__ Wv16,
    _Float16* __restrict__ q16, _Float16* __restrict__ k16,
    _Float16* __restrict__ v16)
{
    __shared__ __align__(16) _Float16 lds[3 * 24576];   // 147456 B

    const int cpx = gridDim.x >> 3;                     // 1152/8 = 144
    int bid = (blockIdx.x & 7) * cpx + (blockIdx.x >> 3);

    const float* A; const _Float16* W; _Float16* O; bool elu;
    int brow, bcol;
    if (bid < 768) {
        A = xq; W = Wq16; O = q16; elu = true;
        brow = bid / 6; bcol = bid - brow * 6;
    } else {
        int u = bid - 768;
        int mat = u / 192;  u -= mat * 192;
        A = xkv; W = mat ? Wv16 : Wk16; O = mat ? v16 : k16; elu = !mat;
        brow = u / 6; bcol = u - brow * 6;
    }
    const int row0 = brow * 256, col0 = bcol * 128;

    float4_t acc[8][2] = {};
    gemm_core<true>(A, W, row0, col0, lds, acc);

    const int wid = threadIdx.x >> 6, lane = threadIdx.x & 63;
    const int wr = wid >> 2, wc = wid & 3, lr = lane & 15, lkg = lane >> 4;
    #pragma unroll
    for (int mi = 0; mi < 8; ++mi) {
        #pragma unroll
        for (int ni = 0; ni < 2; ++ni) {
            #pragma unroll
            for (int e = 0; e < 4; ++e) {
                int r = row0 + wr * 128 + mi * 16 + lkg * 4 + e;
                int c = col0 + wc * 32 + ni * 16 + lr;
                float v = acc[mi][ni][e];
                if (elu) v = (v > 0.0f) ? (v + 1.0f) : __expf(v);  // elu(x)+1
                O[(size_t)r * DIM + c] = (_Float16)v;
            }
        }
    }
}

// ---------------------------------------------------------------------------
// out = attn16 @ Wo.T + bo  (fp32 output), 768 blocks, fp16-A path
// ---------------------------------------------------------------------------
__global__ __launch_bounds__(512) void out_proj(
    const _Float16* __restrict__ a16, const _Float16* __restrict__ Wo16,
    const float* __restrict__ bo, float* __restrict__ out)
{
    __shared__ __align__(16) _Float16 lds[3 * 24576];

    const int cpx = gridDim.x >> 3;                     // 768/8 = 96
    int bid = (blockIdx.x & 7) * cpx + (blockIdx.x >> 3);
    const int brow = bid / 6, bcol = bid - brow * 6;
    const int row0 = brow * 256, col0 = bcol * 128;

    float4_t acc[8][2] = {};
    gemm_core<false>(a16, Wo16, row0, col0, lds, acc);

    const int wid = threadIdx.x >> 6, lane = threadIdx.x & 63;
    const int wr = wid >> 2, wc = wid & 3, lr = lane & 15, lkg = lane >> 4;
    #pragma unroll
    for (int mi = 0; mi < 8; ++mi) {
        #pragma unroll
        for (int ni = 0; ni < 2; ++ni) {
            #pragma unroll
            for (int e = 0; e < 4; ++e) {
                int r = row0 + wr * 128 + mi * 16 + lkg * 4 + e;
                int c = col0 + wc * 32 + ni * 16 + lr;
                out[(size_t)r * DIM + c] = acc[mi][ni][e] + bo[c];
            }
        }
    }
}

// ---------------------------------------------------------------------------
// kv_reduce: per (b,h): kvh[e][d] = sum_n v[n,e]*k[n,d];  ksum[d] = sum_n k[n,d]
// ---------------------------------------------------------------------------
__global__ __launch_bounds__(256) void kv_reduce(const _Float16* __restrict__ k16,
                                                 const _Float16* __restrict__ v16,
                                                 float* __restrict__ kvh,
                                                 float* __restrict__ ksum)
{
    __shared__ __align__(16) _Float16 K[128][64];
    __shared__ __align__(16) _Float16 V[128][64];
    const int chunk = blockIdx.x;   // 0..7
    const int bh    = blockIdx.y;   // 0..95
    const int b = bh / 12, h = bh % 12;
    const int tid = threadIdx.x;

    const size_t base = ((size_t)b * 1024 + (size_t)chunk * 128) * DIM + h * 64;
    #pragma unroll
    for (int j = 0; j < 4; ++j) {
        int idx = j * 256 + tid;
        int r = idx >> 3, c = (idx & 7) * 8;
        *(half8_t*)&K[r][c] = *(const half8_t*)&k16[base + (size_t)r * DIM + c];
        *(half8_t*)&V[r][c] = *(const half8_t*)&v16[base + (size_t)r * DIM + c];
    }
    __syncthreads();

    const int d0 = (tid & 15) * 4;
    const int e0 = (tid >> 4) * 4;
    float acc[4][4] = {};
    #pragma unroll 4
    for (int n = 0; n < 128; ++n) {
        half4_t kd = *(const half4_t*)&K[n][d0];
        half4_t ve = *(const half4_t*)&V[n][e0];
        #pragma unroll
        for (int i = 0; i < 4; ++i)
            #pragma unroll
            for (int j = 0; j < 4; ++j)
                acc[i][j] += (float)ve[i] * (float)kd[j];
    }
    float* kvp = kvh + (size_t)bh * 64 * 64;
    #pragma unroll
    for (int i = 0; i < 4; ++i)
        #pragma unroll
        for (int j = 0; j < 4; ++j)
            atomicAdd(&kvp[(e0 + i) * 64 + d0 + j], acc[i][j]);

    if (tid < 64) {
        float s = 0.0f;
        for (int n = 0; n < 128; ++n) s += (float)K[n][tid];
        atomicAdd(&ksum[bh * 64 + tid], s);
    }
}

// ---------------------------------------------------------------------------
// attn: z = 1/(q . ksum + 1e-6); attn = (q @ kv) * z   (in-place on q16)
// ---------------------------------------------------------------------------
__global__ __launch_bounds__(256) void attn_kernel(_Float16* __restrict__ q16,
                                                   const float* __restrict__ kvh,
                                                   const float* __restrict__ ksum)
{
    __shared__ __align__(16) _Float16 Q[128][72];
    __shared__ __align__(16) _Float16 Bv[64][72];
    __shared__ float S[64];
    __shared__ float Z[128];

    const int h    = blockIdx.x;        // 0..11
    const int rb   = blockIdx.y;        // 0..255
    const int row0 = rb * 128;
    const int b    = row0 >> 12;
    const int bh   = b * 12 + h;
    const int tid  = threadIdx.x;

    #pragma unroll
    for (int j = 0; j < 4; ++j) {
        int idx = j * 256 + tid;
        int r = idx >> 3, c = (idx & 7) * 8;
        *(half8_t*)&Q[r][c] =
            *(const half8_t*)&q16[(size_t)(row0 + r) * DIM + h * 64 + c];
    }
    #pragma unroll
    for (int j = 0; j < 4; ++j) {
        int idx = j * 256 + tid;
        int r = idx >> 4, c = (idx & 15) * 4;
        float4_t f = *(const float4_t*)&kvh[((size_t)bh * 64 + r) * 64 + c];
        half4_t hh;
        #pragma unroll
        for (int e = 0; e < 4; ++e) hh[e] = (_Float16)f[e];
        *(half4_t*)&Bv[r][c] = hh;
    }
    if (tid < 64) S[tid] = ksum[bh * 64 + tid];
    __syncthreads();

    if (tid < 128) {
        float dot = 0.0f;
        #pragma unroll 8
        for (int d = 0; d < 64; ++d) dot += (float)Q[tid][d] * S[d];
        Z[tid] = 1.0f / (dot + 1e-6f);
    }
    __syncthreads();

    const int w = tid >> 6, lane = tid & 63;
    const int lr = lane & 15, lkg = lane >> 4;
    float4_t acc[2][4] = {};
    #pragma unroll
    for (int kc = 0; kc < 2; ++kc) {
        half8_t aF[2], bF[4];
        #pragma unroll
        for (int mi = 0; mi < 2; ++mi)
            aF[mi] = *(const half8_t*)&Q[w * 32 + mi * 16 + lr][kc * 32 + lkg * 8];
        #pragma unroll
        for (int ni = 0; ni < 4; ++ni)
            bF[ni] = *(const half8_t*)&Bv[ni * 16 + lr][kc * 32 + lkg * 8];
        #pragma unroll
        for (int mi = 0; mi < 2; ++mi)
            #pragma unroll
            for (int ni = 0; ni < 4; ++ni)
                acc[mi][ni] = MFMA16(aF[mi], bF[ni], acc[mi][ni]);
    }
    #pragma unroll
    for (int mi = 0; mi < 2; ++mi) {
        #pragma unroll
        for (int ni = 0; ni < 4; ++ni) {
            #pragma unroll
            for (int e = 0; e < 4; ++e) {
                int r = w * 32 + mi * 16 + lkg * 4 + e;
                float v = acc[mi][ni][e] * Z[r];
                q16[(size_t)(row0 + r) * DIM + h * 64 + ni * 16 + lr] = (_Float16)v;
            }
        }
    }
}

// ---------------------------------------------------------------------------
extern "C" void kernel_launch(void* const* d_in, const int* in_sizes, int n_in,
                              void* d_out, int out_size, void* d_ws, size_t ws_size,
                              hipStream_t stream)
{
    const float* xq  = (const float*)d_in[0];  // [8,4096,768]
    const float* xkv = (const float*)d_in[1];  // [8,1024,768]
    const float* Wq  = (const float*)d_in[2];
    const float* Wk  = (const float*)d_in[3];
    const float* Wv  = (const float*)d_in[4];
    const float* Wo  = (const float*)d_in[5];
    const float* bo  = (const float*)d_in[6];

    // ---- workspace layout ----
    char* ws = (char*)d_ws;
    const size_t SZ_Q16  = (size_t)32768 * 768 * 2;   // 50,331,648
    const size_t SZ_W16  = (size_t)768 * 768 * 2;     //  1,179,648
    const size_t SZ_KVH  = (size_t)96 * 64 * 64 * 4;  //  1,572,864
    const size_t SZ_KSUM = (size_t)96 * 64 * 4;       //     24,576

    _Float16* q16  = (_Float16*)(ws);
    _Float16* Wq16 = (_Float16*)(ws + SZ_Q16);
    _Float16* Wk16 = (_Float16*)(ws + SZ_Q16 + SZ_W16);
    _Float16* Wv16 = (_Float16*)(ws + SZ_Q16 + 2 * SZ_W16);
    _Float16* Wo16 = (_Float16*)(ws + SZ_Q16 + 3 * SZ_W16);
    float*    kvh  = (float*)   (ws + SZ_Q16 + 4 * SZ_W16);
    float*    ksum = (float*)   (ws + SZ_Q16 + 4 * SZ_W16 + SZ_KVH);

    // ---- d_out aliasing: k16/v16 consumed (kv_reduce) before out_proj ----
    char* ob = (char*)d_out;
    _Float16* k16 = (_Float16*)(ob + 50331648);
    _Float16* v16 = (_Float16*)(ob + 50331648 + 12582912);
    float*    out = (float*)d_out;

    // 1) weight cast + kv accumulator clear
    cast4_f32_f16<<<dim3(288, 4), 256, 0, stream>>>(Wq, Wk, Wv, Wo,
                                                    Wq16, Wk16, Wv16, Wo16);
    hipMemsetAsync(kvh, 0, SZ_KVH + SZ_KSUM, stream);

    // 2) fused projections straight from fp32 activations
    proj_qkv<<<1152, 512, 0, stream>>>(xq, xkv, Wq16, Wk16, Wv16,
                                       q16, k16, v16);

    // 3) linear attention
    kv_reduce<<<dim3(8, 96), 256, 0, stream>>>(k16, v16, kvh, ksum);
    attn_kernel<<<dim3(12, 256), 256, 0, stream>>>(q16, kvh, ksum);

    // 4) out = attn @ Wo.T + bo  (fp32 output)
    out_proj<<<768, 512, 0, stream>>>(q16, Wo16, bo, out);
}

// Round 7
// 292.618 us; speedup vs baseline: 1.1566x; 1.1566x over previous
//
#include <hip/hip_runtime.h>

typedef _Float16 half8_t __attribute__((ext_vector_type(8)));
typedef _Float16 half4_t __attribute__((ext_vector_type(4)));
typedef float    float4_t __attribute__((ext_vector_type(4)));

#define DIM 768

// async global->LDS, 16B per lane; LDS dest is wave-uniform base + lane*16
#define GLOAD16(g, l) __builtin_amdgcn_global_load_lds(                        \
    (const __attribute__((address_space(1))) void*)(g),                        \
    (__attribute__((address_space(3))) void*)(l), 16, 0, 0)

#define MFMA16(a, b, c) __builtin_amdgcn_mfma_f32_16x16x32_f16((a), (b), (c), 0, 0, 0)

// ---------------------------------------------------------------------------
// activation cast: xq (3,145,728 half8) then xkv (786,432 half8), one launch
// ---------------------------------------------------------------------------
__global__ __launch_bounds__(256) void cast_acts(const float* __restrict__ xq,
                                                 const float* __restrict__ xkv,
                                                 _Float16* __restrict__ dq,
                                                 _Float16* __restrict__ dkv)
{
    int i = blockIdx.x * 256 + threadIdx.x;     // grid = 15360*256 = 3,932,160
    const float* s; _Float16* d; int off;
    if (i < 3145728) { s = xq;  d = dq;  off = i; }
    else             { s = xkv; d = dkv; off = i - 3145728; }
    float4_t f0 = *(const float4_t*)&s[(size_t)off * 8];
    float4_t f1 = *(const float4_t*)&s[(size_t)off * 8 + 4];
    half8_t h;
    #pragma unroll
    for (int e = 0; e < 4; ++e) { h[e] = (_Float16)f0[e]; h[e + 4] = (_Float16)f1[e]; }
    *(half8_t*)&d[(size_t)off * 8] = h;
}

// weight cast (tiny: 4 x 768x768)
__global__ __launch_bounds__(256) void cast4_f32_f16(
    const float* __restrict__ s0, const float* __restrict__ s1,
    const float* __restrict__ s2, const float* __restrict__ s3,
    _Float16* __restrict__ d0, _Float16* __restrict__ d1,
    _Float16* __restrict__ d2, _Float16* __restrict__ d3)
{
    const float* s; _Float16* d;
    switch (blockIdx.y) {
        case 0: s = s0; d = d0; break;
        case 1: s = s1; d = d1; break;
        case 2: s = s2; d = d2; break;
        default: s = s3; d = d3; break;
    }
    int i = blockIdx.x * 256 + threadIdx.x;
    float4_t f0 = *(const float4_t*)&s[(size_t)i * 8];
    float4_t f1 = *(const float4_t*)&s[(size_t)i * 8 + 4];
    half8_t h;
    #pragma unroll
    for (int e = 0; e < 4; ++e) { h[e] = (_Float16)f0[e]; h[e + 4] = (_Float16)f1[e]; }
    *(half8_t*)&d[(size_t)i * 8] = h;
}

// ---------------------------------------------------------------------------
// GEMM core: out tile 128x128, BK=64, 12 K-tiles, 256 thr = 4 waves (2x2),
// per-wave C 64x64 (acc[4][4] = 64 VGPR) -- square wave-tile minimizes
// LDS-bytes/FLOP ((m+n)/(mn) = 1/32 vs r4's 1/25.6).
// LDS: 2 slots x 32KB = 64KB -> 2 blocks/CU (independent barrier domains
// overlap each other's stalls -- the r4 structure's main loss at 1 blk/CU).
// Chunk layout (r5-proven, conflict-free): chunk = 1KB = 16 rows x 32 halves,
// granule-transposed (16B-slot g holds row=g&15, koct=g>>4); A = chunks 0..15,
// B = chunks 16..31. Frag read = chunk_base + lane*16B (contiguous 1KB/wave,
// 0 bank conflicts, exact MFMA fragment layout).
// Schedule per tile (ONE barrier, ONE vmcnt):
//   ds_read 16 frags (compiler lgkm) ; 32 MFMA ;
//   vmcnt(0)   <- drains STAGE(t+1), issued a full tile earlier (cheap) ;
//   s_barrier  <- all waves done reading slot s ;
//   STAGE(t+2, s)  <- safe overwrite, lands during tile t+1.
// ---------------------------------------------------------------------------
__device__ __forceinline__ void gemm_core(const _Float16* __restrict__ A,
                                          const _Float16* __restrict__ W,
                                          int row0, int col0,
                                          _Float16* lds, float4_t acc[4][4])
{
    const int tid  = threadIdx.x;
    const int wid  = tid >> 6, lane = tid & 63;
    const int wr   = wid >> 1, wc = wid & 1;

    // staging sources: wave wid stages A chunks {4wid..4wid+3}, B likewise.
    // chunk 4wid+j: rowgroup rg = 2wid + (j>>1), k-half q = j&1;
    // lane -> (row = lane&15, koct = lane>>4)  [per-lane global addr]
    const _Float16* Ast[4];
    const _Float16* Bst[4];
    #pragma unroll
    for (int j = 0; j < 4; ++j) {
        const int rr = (2 * wid + (j >> 1)) * 16 + (lane & 15);
        const int k0 = (j & 1) * 32 + (lane >> 4) * 8;
        Ast[j] = A + (size_t)(row0 + rr) * DIM + k0;
        Bst[j] = W + (size_t)(col0 + rr) * DIM + k0;
    }

#define STAGE(t, s) do { _Pragma("unroll")                                     \
        for (int j = 0; j < 4; ++j)                                            \
            GLOAD16(Ast[j] + (t) * 64, &lds[(s) * 16384 + (4*wid + j) * 512]); \
        _Pragma("unroll")                                                      \
        for (int j = 0; j < 4; ++j)                                            \
            GLOAD16(Bst[j] + (t) * 64,                                         \
                    &lds[(s) * 16384 + 8192 + (4*wid + j) * 512]);             \
    } while (0)

    // prologue: tile0 -> slot0, tile1 -> slot1
    STAGE(0, 0);
    __builtin_amdgcn_sched_barrier(0);
    STAGE(1, 1);
    asm volatile("s_waitcnt vmcnt(8)" ::: "memory");   // tile0 landed
    __builtin_amdgcn_s_barrier();
    __builtin_amdgcn_sched_barrier(0);

    #pragma unroll
    for (int t = 0; t < 12; ++t) {
        const int sb = (t & 1) * 16384;
        half8_t af[4][2], bf[4][2];
        #pragma unroll
        for (int mi = 0; mi < 4; ++mi) {
            af[mi][0] = *(const half8_t*)&lds[sb + ((wr*4 + mi)*2    )*512 + lane*8];
            af[mi][1] = *(const half8_t*)&lds[sb + ((wr*4 + mi)*2 + 1)*512 + lane*8];
        }
        #pragma unroll
        for (int ni = 0; ni < 4; ++ni) {
            bf[ni][0] = *(const half8_t*)&lds[sb + 8192 + ((wc*4 + ni)*2    )*512 + lane*8];
            bf[ni][1] = *(const half8_t*)&lds[sb + 8192 + ((wc*4 + ni)*2 + 1)*512 + lane*8];
        }
        __builtin_amdgcn_s_setprio(1);
        #pragma unroll
        for (int mi = 0; mi < 4; ++mi)
            #pragma unroll
            for (int ni = 0; ni < 4; ++ni) {
                acc[mi][ni] = MFMA16(af[mi][0], bf[ni][0], acc[mi][ni]);
                acc[mi][ni] = MFMA16(af[mi][1], bf[ni][1], acc[mi][ni]);
            }
        __builtin_amdgcn_s_setprio(0);

        if (t < 11) {
            asm volatile("s_waitcnt vmcnt(0)" ::: "memory");  // tile t+1 landed
            __builtin_amdgcn_s_barrier();                     // slot s free
            __builtin_amdgcn_sched_barrier(0);
            if (t < 10) STAGE(t + 2, t & 1);
        }
    }
#undef STAGE
}

// ---------------------------------------------------------------------------
// Fused q/k/v projection: 2304 blocks (128-row tiles).
//   bid <  1536 : q = elu1(xq @ Wq.T)   (256 row-blocks x 6)
//   1536..1919  : k = elu1(xkv @ Wk.T)  ( 64 row-blocks x 6)
//   1920..2303  : v =      xkv @ Wv.T
// ---------------------------------------------------------------------------
__global__ __launch_bounds__(256, 2) void proj_qkv(
    const _Float16* __restrict__ xq16, const _Float16* __restrict__ xkv16,
    const _Float16* __restrict__ Wq16, const _Float16* __restrict__ Wk16,
    const _Float16* __restrict__ Wv16,
    _Float16* __restrict__ q16, _Float16* __restrict__ k16,
    _Float16* __restrict__ v16)
{
    __shared__ __align__(16) _Float16 lds[2 * 16384];   // 65536 B

    const int cpx = gridDim.x >> 3;                     // 2304/8 = 288
    int bid = (blockIdx.x & 7) * cpx + (blockIdx.x >> 3);

    const _Float16 *A, *W; _Float16* O; bool elu;
    int brow, bcol;
    if (bid < 1536) {
        A = xq16; W = Wq16; O = q16; elu = true;
        brow = bid / 6; bcol = bid - brow * 6;
    } else {
        int u = bid - 1536;
        int mat = u / 384;  u -= mat * 384;
        A = xkv16; W = mat ? Wv16 : Wk16; O = mat ? v16 : k16; elu = !mat;
        brow = u / 6; bcol = u - brow * 6;
    }
    const int row0 = brow * 128, col0 = bcol * 128;

    float4_t acc[4][4] = {};
    gemm_core(A, W, row0, col0, lds, acc);

    const int wid = threadIdx.x >> 6, lane = threadIdx.x & 63;
    const int wr = wid >> 1, wc = wid & 1, lr = lane & 15, lkg = lane >> 4;
    #pragma unroll
    for (int mi = 0; mi < 4; ++mi) {
        #pragma unroll
        for (int ni = 0; ni < 4; ++ni) {
            #pragma unroll
            for (int e = 0; e < 4; ++e) {
                int r = row0 + wr * 64 + mi * 16 + lkg * 4 + e;
                int c = col0 + wc * 64 + ni * 16 + lr;
                float v = acc[mi][ni][e];
                if (elu) v = (v > 0.0f) ? (v + 1.0f) : __expf(v);  // elu(x)+1
                O[(size_t)r * DIM + c] = (_Float16)v;
            }
        }
    }
}

// ---------------------------------------------------------------------------
// out = attn16 @ Wo.T + bo  (fp32 output), 1536 blocks
// ---------------------------------------------------------------------------
__global__ __launch_bounds__(256, 2) void out_proj(
    const _Float16* __restrict__ a16, const _Float16* __restrict__ Wo16,
    const float* __restrict__ bo, float* __restrict__ out)
{
    __shared__ __align__(16) _Float16 lds[2 * 16384];

    const int cpx = gridDim.x >> 3;                     // 1536/8 = 192
    int bid = (blockIdx.x & 7) * cpx + (blockIdx.x >> 3);
    const int brow = bid / 6, bcol = bid - brow * 6;
    const int row0 = brow * 128, col0 = bcol * 128;

    float4_t acc[4][4] = {};
    gemm_core(a16, Wo16, row0, col0, lds, acc);

    const int wid = threadIdx.x >> 6, lane = threadIdx.x & 63;
    const int wr = wid >> 1, wc = wid & 1, lr = lane & 15, lkg = lane >> 4;
    #pragma unroll
    for (int mi = 0; mi < 4; ++mi) {
        #pragma unroll
        for (int ni = 0; ni < 4; ++ni) {
            #pragma unroll
            for (int e = 0; e < 4; ++e) {
                int r = row0 + wr * 64 + mi * 16 + lkg * 4 + e;
                int c = col0 + wc * 64 + ni * 16 + lr;
                out[(size_t)r * DIM + c] = acc[mi][ni][e] + bo[c];
            }
        }
    }
}

// ---------------------------------------------------------------------------
// kv_reduce: per (b,h): kvh[e][d] = sum_n v[n,e]*k[n,d];  ksum[d] = sum_n k[n,d]
// ---------------------------------------------------------------------------
__global__ __launch_bounds__(256) void kv_reduce(const _Float16* __restrict__ k16,
                                                 const _Float16* __restrict__ v16,
                                                 float* __restrict__ kvh,
                                                 float* __restrict__ ksum)
{
    __shared__ __align__(16) _Float16 K[128][64];
    __shared__ __align__(16) _Float16 V[128][64];
    const int chunk = blockIdx.x;   // 0..7
    const int bh    = blockIdx.y;   // 0..95
    const int b = bh / 12, h = bh % 12;
    const int tid = threadIdx.x;

    const size_t base = ((size_t)b * 1024 + (size_t)chunk * 128) * DIM + h * 64;
    #pragma unroll
    for (int j = 0; j < 4; ++j) {
        int idx = j * 256 + tid;
        int r = idx >> 3, c = (idx & 7) * 8;
        *(half8_t*)&K[r][c] = *(const half8_t*)&k16[base + (size_t)r * DIM + c];
        *(half8_t*)&V[r][c] = *(const half8_t*)&v16[base + (size_t)r * DIM + c];
    }
    __syncthreads();

    const int d0 = (tid & 15) * 4;
    const int e0 = (tid >> 4) * 4;
    float acc[4][4] = {};
    #pragma unroll 4
    for (int n = 0; n < 128; ++n) {
        half4_t kd = *(const half4_t*)&K[n][d0];
        half4_t ve = *(const half4_t*)&V[n][e0];
        #pragma unroll
        for (int i = 0; i < 4; ++i)
            #pragma unroll
            for (int j = 0; j < 4; ++j)
                acc[i][j] += (float)ve[i] * (float)kd[j];
    }
    float* kvp = kvh + (size_t)bh * 64 * 64;
    #pragma unroll
    for (int i = 0; i < 4; ++i)
        #pragma unroll
        for (int j = 0; j < 4; ++j)
            atomicAdd(&kvp[(e0 + i) * 64 + d0 + j], acc[i][j]);

    if (tid < 64) {
        float s = 0.0f;
        for (int n = 0; n < 128; ++n) s += (float)K[n][tid];
        atomicAdd(&ksum[bh * 64 + tid], s);
    }
}

// ---------------------------------------------------------------------------
// attn: z = 1/(q . ksum + 1e-6); attn = (q @ kv) * z   (in-place on q16)
// ---------------------------------------------------------------------------
__global__ __launch_bounds__(256) void attn_kernel(_Float16* __restrict__ q16,
                                                   const float* __restrict__ kvh,
                                                   const float* __restrict__ ksum)
{
    __shared__ __align__(16) _Float16 Q[128][72];
    __shared__ __align__(16) _Float16 Bv[64][72];
    __shared__ float S[64];
    __shared__ float Z[128];

    const int h    = blockIdx.x;        // 0..11
    const int rb   = blockIdx.y;        // 0..255
    const int row0 = rb * 128;
    const int b    = row0 >> 12;
    const int bh   = b * 12 + h;
    const int tid  = threadIdx.x;

    #pragma unroll
    for (int j = 0; j < 4; ++j) {
        int idx = j * 256 + tid;
        int r = idx >> 3, c = (idx & 7) * 8;
        *(half8_t*)&Q[r][c] =
            *(const half8_t*)&q16[(size_t)(row0 + r) * DIM + h * 64 + c];
    }
    #pragma unroll
    for (int j = 0; j < 4; ++j) {
        int idx = j * 256 + tid;
        int r = idx >> 4, c = (idx & 15) * 4;
        float4_t f = *(const float4_t*)&kvh[((size_t)bh * 64 + r) * 64 + c];
        half4_t hh;
        #pragma unroll
        for (int e = 0; e < 4; ++e) hh[e] = (_Float16)f[e];
        *(half4_t*)&Bv[r][c] = hh;
    }
    if (tid < 64) S[tid] = ksum[bh * 64 + tid];
    __syncthreads();

    if (tid < 128) {
        float dot = 0.0f;
        #pragma unroll 8
        for (int d = 0; d < 64; ++d) dot += (float)Q[tid][d] * S[d];
        Z[tid] = 1.0f / (dot + 1e-6f);
    }
    __syncthreads();

    const int w = tid >> 6, lane = tid & 63;
    const int lr = lane & 15, lkg = lane >> 4;
    float4_t acc[2][4] = {};
    #pragma unroll
    for (int kc = 0; kc < 2; ++kc) {
        half8_t aF[2], bF[4];
        #pragma unroll
        for (int mi = 0; mi < 2; ++mi)
            aF[mi] = *(const half8_t*)&Q[w * 32 + mi * 16 + lr][kc * 32 + lkg * 8];
        #pragma unroll
        for (int ni = 0; ni < 4; ++ni)
            bF[ni] = *(const half8_t*)&Bv[ni * 16 + lr][kc * 32 + lkg * 8];
        #pragma unroll
        for (int mi = 0; mi < 2; ++mi)
            #pragma unroll
            for (int ni = 0; ni < 4; ++ni)
                acc[mi][ni] = MFMA16(aF[mi], bF[ni], acc[mi][ni]);
    }
    #pragma unroll
    for (int mi = 0; mi < 2; ++mi) {
        #pragma unroll
        for (int ni = 0; ni < 4; ++ni) {
            #pragma unroll
            for (int e = 0; e < 4; ++e) {
                int r = w * 32 + mi * 16 + lkg * 4 + e;
                float v = acc[mi][ni][e] * Z[r];
                q16[(size_t)(row0 + r) * DIM + h * 64 + ni * 16 + lr] = (_Float16)v;
            }
        }
    }
}

// ---------------------------------------------------------------------------
extern "C" void kernel_launch(void* const* d_in, const int* in_sizes, int n_in,
                              void* d_out, int out_size, void* d_ws, size_t ws_size,
                              hipStream_t stream)
{
    const float* xq  = (const float*)d_in[0];  // [8,4096,768]
    const float* xkv = (const float*)d_in[1];  // [8,1024,768]
    const float* Wq  = (const float*)d_in[2];
    const float* Wk  = (const float*)d_in[3];
    const float* Wv  = (const float*)d_in[4];
    const float* Wo  = (const float*)d_in[5];
    const float* bo  = (const float*)d_in[6];

    // ---- workspace layout (~69 MB) ----
    char* ws = (char*)d_ws;
    const size_t SZ_Q16   = (size_t)32768 * 768 * 2;   // 50,331,648
    const size_t SZ_XKV16 = (size_t)8192 * 768 * 2;    // 12,582,912
    const size_t SZ_W16   = (size_t)768 * 768 * 2;     //  1,179,648
    const size_t SZ_KVH   = (size_t)96 * 64 * 64 * 4;  //  1,572,864
    const size_t SZ_KSUM  = (size_t)96 * 64 * 4;       //     24,576

    _Float16* q16   = (_Float16*)(ws);
    _Float16* xkv16 = (_Float16*)(ws + SZ_Q16);
    _Float16* Wq16  = (_Float16*)(ws + SZ_Q16 + SZ_XKV16);
    _Float16* Wk16  = (_Float16*)(ws + SZ_Q16 + SZ_XKV16 + SZ_W16);
    _Float16* Wv16  = (_Float16*)(ws + SZ_Q16 + SZ_XKV16 + 2 * SZ_W16);
    _Float16* Wo16  = (_Float16*)(ws + SZ_Q16 + SZ_XKV16 + 3 * SZ_W16);
    float*    kvh   = (float*)   (ws + SZ_Q16 + SZ_XKV16 + 4 * SZ_W16);
    float*    ksum  = (float*)   (ws + SZ_Q16 + SZ_XKV16 + 4 * SZ_W16 + SZ_KVH);

    // ---- d_out aliasing: xq16 consumed by proj_qkv; k16/v16 by kv_reduce;
    //      all dead before out_proj overwrites d_out. ----
    char* ob = (char*)d_out;
    _Float16* xq16 = (_Float16*)(ob);                       // 50,331,648
    _Float16* k16  = (_Float16*)(ob + 50331648);            // 12,582,912
    _Float16* v16  = (_Float16*)(ob + 50331648 + 12582912); // 12,582,912
    float*    out  = (float*)d_out;

    // 1) casts + kv accumulator clear
    cast_acts<<<15360, 256, 0, stream>>>(xq, xkv, xq16, xkv16);
    cast4_f32_f16<<<dim3(288, 4), 256, 0, stream>>>(Wq, Wk, Wv, Wo,
                                                    Wq16, Wk16, Wv16, Wo16);
    hipMemsetAsync(kvh, 0, SZ_KVH + SZ_KSUM, stream);

    // 2) fused projections: q = elu1(xq@Wq.T), k = elu1(xkv@Wk.T), v = xkv@Wv.T
    proj_qkv<<<2304, 256, 0, stream>>>(xq16, xkv16, Wq16, Wk16, Wv16,
                                       q16, k16, v16);

    // 3) linear attention
    kv_reduce<<<dim3(8, 96), 256, 0, stream>>>(k16, v16, kvh, ksum);
    attn_kernel<<<dim3(12, 256), 256, 0, stream>>>(q16, kvh, ksum);

    // 4) out = attn @ Wo.T + bo  (fp32 output)
    out_proj<<<1536, 256, 0, stream>>>(q16, Wo16, bo, out);
}

// Round 8
// 266.708 us; speedup vs baseline: 1.2690x; 1.0971x over previous
//
#include <hip/hip_runtime.h>

typedef _Float16 half8_t __attribute__((ext_vector_type(8)));
typedef _Float16 half4_t __attribute__((ext_vector_type(4)));
typedef float    float4_t __attribute__((ext_vector_type(4)));

#define DIM 768

// async global->LDS, 16B per lane; LDS dest is wave-uniform base + lane*16
#define GLOAD16(g, l) __builtin_amdgcn_global_load_lds(                        \
    (const __attribute__((address_space(1))) void*)(g),                        \
    (__attribute__((address_space(3))) void*)(l), 16, 0, 0)

#define MFMA16(a, b, c) __builtin_amdgcn_mfma_f32_16x16x32_f16((a), (b), (c), 0, 0, 0)

// ---------------------------------------------------------------------------
// one fused cast launch: xq (3,145,728 half8) | xkv (786,432) | weights
// (4 x 73,728; dests contiguous in ws starting at Wq16)
// ---------------------------------------------------------------------------
__global__ __launch_bounds__(256) void cast_all(
    const float* __restrict__ xq,  const float* __restrict__ xkv,
    const float* __restrict__ Wq,  const float* __restrict__ Wk,
    const float* __restrict__ Wv,  const float* __restrict__ Wo,
    _Float16* __restrict__ dq, _Float16* __restrict__ dkv,
    _Float16* __restrict__ dW /* 4 matrices contiguous */)
{
    int i = blockIdx.x * 256 + threadIdx.x;    // grid 16512*256 = 4,227,072
    const float* s; _Float16* d; int off;
    if (i < 3145728)      { s = xq;  d = dq;  off = i; }
    else if (i < 3932160) { s = xkv; d = dkv; off = i - 3145728; }
    else {
        int j = i - 3932160;                   // 0..294911
        int w = j / 73728;  off = j - w * 73728;
        s = (w == 0) ? Wq : (w == 1) ? Wk : (w == 2) ? Wv : Wo;
        d = dW + (size_t)w * 589824;
    }
    float4_t f0 = *(const float4_t*)&s[(size_t)off * 8];
    float4_t f1 = *(const float4_t*)&s[(size_t)off * 8 + 4];
    half8_t h;
    #pragma unroll
    for (int e = 0; e < 4; ++e) { h[e] = (_Float16)f0[e]; h[e + 4] = (_Float16)f1[e]; }
    *(half8_t*)&d[(size_t)off * 8] = h;
}

// ---------------------------------------------------------------------------
// GEMM core -- catalog minimal-2-phase (T3 recipe, measured 655-682 TF band):
// out tile 256x256, BK=64, 12 K-tiles, 512 thr = 8 waves (2M x 4N),
// per-wave C 128x64 (acc[8][4]); LDS 2 buffers x 64KB = 128KB (1 block/CU).
// Chunk-transposed layout (r5/r7-proven, 0 bank conflicts): chunk = 1KB =
// 16 rows x 32 halves, 16B-slot g holds (row=g&15, koct=g>>4).
//   A chunks 0..31 (id = rowgroup*2 + khalf), B chunks 32..63 likewise.
//   frag read = chunk_base + lane*16B  (contiguous 1KB/wave, MFMA-exact).
// Per tile: STAGE(t+1 -> buf^1) FIRST (8 gload_lds/thread), then ds_read +
// 64 MFMA from buf, then __syncthreads() (vmcnt(0)+barrier: tile t+1 landed,
// buf readers done -> next STAGE may overwrite). One sync point per tile.
// ---------------------------------------------------------------------------
__device__ __forceinline__ void gemm_core(const _Float16* __restrict__ A,
                                          const _Float16* __restrict__ W,
                                          int row0, int col0,
                                          _Float16* lds, float4_t acc[8][4])
{
    const int tid  = threadIdx.x;
    const int wid  = tid >> 6, lane = tid & 63;
    const int wr   = wid >> 2;           // 0..1 : 128-row half
    const int wc   = wid & 3;            // 0..3 : 64-col quarter

    // staging: wave wid owns A chunks 4wid..4wid+3 and B chunks 4wid..4wid+3
    // chunk 4wid+j: rowgroup rg = 2wid+(j>>1), khalf q = j&1
    // lane -> (row = lane&15, koct = lane>>4)  [per-lane global address]
    const _Float16* Ast[4];
    const _Float16* Bst[4];
    #pragma unroll
    for (int j = 0; j < 4; ++j) {
        const int rr = (2 * wid + (j >> 1)) * 16 + (lane & 15);
        const int k0 = (j & 1) * 32 + (lane >> 4) * 8;
        Ast[j] = A + (size_t)(row0 + rr) * DIM + k0;
        Bst[j] = W + (size_t)(col0 + rr) * DIM + k0;
    }

#define STAGE(t, b) do { _Pragma("unroll")                                     \
        for (int j = 0; j < 4; ++j) {                                          \
            GLOAD16(Ast[j] + (t) * 64,                                         \
                    &lds[(b) * 32768 + (4*wid + j) * 512]);                    \
            GLOAD16(Bst[j] + (t) * 64,                                         \
                    &lds[(b) * 32768 + 16384 + (4*wid + j) * 512]);            \
        } } while (0)

    // prologue (catalog): STAGE(buf0, t=0); vmcnt(0); barrier
    STAGE(0, 0);
    __syncthreads();

    #pragma unroll
    for (int t = 0; t < 12; ++t) {
        const int sb = (t & 1) * 32768;
        if (t < 11) STAGE(t + 1, (t & 1) ^ 1);   // issue-early, before reads

        // B frags: ni 0..3, kk 0..1  (chunk rg = wc*4+ni)
        half8_t bf[4][2];
        #pragma unroll
        for (int ni = 0; ni < 4; ++ni) {
            bf[ni][0] = *(const half8_t*)&lds[sb + 16384 + ((wc*4 + ni)*2    )*512 + lane*8];
            bf[ni][1] = *(const half8_t*)&lds[sb + 16384 + ((wc*4 + ni)*2 + 1)*512 + lane*8];
        }
        __builtin_amdgcn_s_setprio(1);
        #pragma unroll
        for (int mi = 0; mi < 8; ++mi) {
            half8_t af0 = *(const half8_t*)&lds[sb + ((wr*8 + mi)*2    )*512 + lane*8];
            half8_t af1 = *(const half8_t*)&lds[sb + ((wr*8 + mi)*2 + 1)*512 + lane*8];
            #pragma unroll
            for (int ni = 0; ni < 4; ++ni) {
                acc[mi][ni] = MFMA16(af0, bf[ni][0], acc[mi][ni]);
                acc[mi][ni] = MFMA16(af1, bf[ni][1], acc[mi][ni]);
            }
        }
        __builtin_amdgcn_s_setprio(0);

        __syncthreads();   // = vmcnt(0)+lgkm(0)+s_barrier: t+1 landed, buf free
    }
#undef STAGE
}

// ---------------------------------------------------------------------------
// Fused q/k/v projection: 576 blocks (256-row x 256-col tiles, 3 col-tiles).
//   bid <  384 : q = elu1(xq @ Wq.T)   (128 row-blocks x 3)
//   384..479   : k = elu1(xkv @ Wk.T)  ( 32 row-blocks x 3)
//   480..575   : v =      xkv @ Wv.T
// ---------------------------------------------------------------------------
__global__ __launch_bounds__(512) void proj_qkv(
    const _Float16* __restrict__ xq16, const _Float16* __restrict__ xkv16,
    const _Float16* __restrict__ Wq16, const _Float16* __restrict__ Wk16,
    const _Float16* __restrict__ Wv16,
    _Float16* __restrict__ q16, _Float16* __restrict__ k16,
    _Float16* __restrict__ v16)
{
    __shared__ __align__(16) _Float16 lds[2 * 32768];   // 131072 B

    const int cpx = gridDim.x >> 3;                     // 576/8 = 72
    int bid = (blockIdx.x & 7) * cpx + (blockIdx.x >> 3);

    const _Float16 *A, *W; _Float16* O; bool elu;
    int brow, bcol;
    if (bid < 384) {
        A = xq16; W = Wq16; O = q16; elu = true;
        brow = bid / 3; bcol = bid - brow * 3;
    } else {
        int u = bid - 384;
        int mat = u / 96;  u -= mat * 96;
        A = xkv16; W = mat ? Wv16 : Wk16; O = mat ? v16 : k16; elu = !mat;
        brow = u / 3; bcol = u - brow * 3;
    }
    const int row0 = brow * 256, col0 = bcol * 256;

    float4_t acc[8][4] = {};
    gemm_core(A, W, row0, col0, lds, acc);

    const int wid = threadIdx.x >> 6, lane = threadIdx.x & 63;
    const int wr = wid >> 2, wc = wid & 3, lr = lane & 15, lkg = lane >> 4;
    #pragma unroll
    for (int mi = 0; mi < 8; ++mi) {
        #pragma unroll
        for (int ni = 0; ni < 4; ++ni) {
            #pragma unroll
            for (int e = 0; e < 4; ++e) {
                int r = row0 + wr * 128 + mi * 16 + lkg * 4 + e;
                int c = col0 + wc * 64 + ni * 16 + lr;
                float v = acc[mi][ni][e];
                if (elu) v = (v > 0.0f) ? (v + 1.0f) : __expf(v);  // elu(x)+1
                O[(size_t)r * DIM + c] = (_Float16)v;
            }
        }
    }
}

// ---------------------------------------------------------------------------
// out = attn16 @ Wo.T + bo  (fp32 output), 384 blocks
// ---------------------------------------------------------------------------
__global__ __launch_bounds__(512) void out_proj(
    const _Float16* __restrict__ a16, const _Float16* __restrict__ Wo16,
    const float* __restrict__ bo, float* __restrict__ out)
{
    __shared__ __align__(16) _Float16 lds[2 * 32768];

    const int cpx = gridDim.x >> 3;                     // 384/8 = 48
    int bid = (blockIdx.x & 7) * cpx + (blockIdx.x >> 3);
    const int brow = bid / 3, bcol = bid - brow * 3;
    const int row0 = brow * 256, col0 = bcol * 256;

    float4_t acc[8][4] = {};
    gemm_core(a16, Wo16, row0, col0, lds, acc);

    const int wid = threadIdx.x >> 6, lane = threadIdx.x & 63;
    const int wr = wid >> 2, wc = wid & 3, lr = lane & 15, lkg = lane >> 4;
    #pragma unroll
    for (int mi = 0; mi < 8; ++mi) {
        #pragma unroll
        for (int ni = 0; ni < 4; ++ni) {
            #pragma unroll
            for (int e = 0; e < 4; ++e) {
                int r = row0 + wr * 128 + mi * 16 + lkg * 4 + e;
                int c = col0 + wc * 64 + ni * 16 + lr;
                out[(size_t)r * DIM + c] = acc[mi][ni][e] + bo[c];
            }
        }
    }
}

// ---------------------------------------------------------------------------
// kv_reduce: per (b,h): kvh[e][d] = sum_n v[n,e]*k[n,d];  ksum[d] = sum_n k[n,d]
// ---------------------------------------------------------------------------
__global__ __launch_bounds__(256) void kv_reduce(const _Float16* __restrict__ k16,
                                                 const _Float16* __restrict__ v16,
                                                 float* __restrict__ kvh,
                                                 float* __restrict__ ksum)
{
    __shared__ __align__(16) _Float16 K[128][64];
    __shared__ __align__(16) _Float16 V[128][64];
    const int chunk = blockIdx.x;   // 0..7
    const int bh    = blockIdx.y;   // 0..95
    const int b = bh / 12, h = bh % 12;
    const int tid = threadIdx.x;

    const size_t base = ((size_t)b * 1024 + (size_t)chunk * 128) * DIM + h * 64;
    #pragma unroll
    for (int j = 0; j < 4; ++j) {
        int idx = j * 256 + tid;
        int r = idx >> 3, c = (idx & 7) * 8;
        *(half8_t*)&K[r][c] = *(const half8_t*)&k16[base + (size_t)r * DIM + c];
        *(half8_t*)&V[r][c] = *(const half8_t*)&v16[base + (size_t)r * DIM + c];
    }
    __syncthreads();

    const int d0 = (tid & 15) * 4;
    const int e0 = (tid >> 4) * 4;
    float acc[4][4] = {};
    #pragma unroll 4
    for (int n = 0; n < 128; ++n) {
        half4_t kd = *(const half4_t*)&K[n][d0];
        half4_t ve = *(const half4_t*)&V[n][e0];
        #pragma unroll
        for (int i = 0; i < 4; ++i)
            #pragma unroll
            for (int j = 0; j < 4; ++j)
                acc[i][j] += (float)ve[i] * (float)kd[j];
    }
    float* kvp = kvh + (size_t)bh * 64 * 64;
    #pragma unroll
    for (int i = 0; i < 4; ++i)
        #pragma unroll
        for (int j = 0; j < 4; ++j)
            atomicAdd(&kvp[(e0 + i) * 64 + d0 + j], acc[i][j]);

    if (tid < 64) {
        float s = 0.0f;
        for (int n = 0; n < 128; ++n) s += (float)K[n][tid];
        atomicAdd(&ksum[bh * 64 + tid], s);
    }
}

// ---------------------------------------------------------------------------
// attn: z = 1/(q . ksum + 1e-6); attn = (q @ kv) * z   (in-place on q16)
// ---------------------------------------------------------------------------
__global__ __launch_bounds__(256) void attn_kernel(_Float16* __restrict__ q16,
                                                   const float* __restrict__ kvh,
                                                   const float* __restrict__ ksum)
{
    __shared__ __align__(16) _Float16 Q[128][72];
    __shared__ __align__(16) _Float16 Bv[64][72];
    __shared__ float S[64];
    __shared__ float Z[128];

    const int h    = blockIdx.x;        // 0..11
    const int rb   = blockIdx.y;        // 0..255
    const int row0 = rb * 128;
    const int b    = row0 >> 12;
    const int bh   = b * 12 + h;
    const int tid  = threadIdx.x;

    #pragma unroll
    for (int j = 0; j < 4; ++j) {
        int idx = j * 256 + tid;
        int r = idx >> 3, c = (idx & 7) * 8;
        *(half8_t*)&Q[r][c] =
            *(const half8_t*)&q16[(size_t)(row0 + r) * DIM + h * 64 + c];
    }
    #pragma unroll
    for (int j = 0; j < 4; ++j) {
        int idx = j * 256 + tid;
        int r = idx >> 4, c = (idx & 15) * 4;
        float4_t f = *(const float4_t*)&kvh[((size_t)bh * 64 + r) * 64 + c];
        half4_t hh;
        #pragma unroll
        for (int e = 0; e < 4; ++e) hh[e] = (_Float16)f[e];
        *(half4_t*)&Bv[r][c] = hh;
    }
    if (tid < 64) S[tid] = ksum[bh * 64 + tid];
    __syncthreads();

    if (tid < 128) {
        float dot = 0.0f;
        #pragma unroll 8
        for (int d = 0; d < 64; ++d) dot += (float)Q[tid][d] * S[d];
        Z[tid] = 1.0f / (dot + 1e-6f);
    }
    __syncthreads();

    const int w = tid >> 6, lane = tid & 63;
    const int lr = lane & 15, lkg = lane >> 4;
    float4_t acc[2][4] = {};
    #pragma unroll
    for (int kc = 0; kc < 2; ++kc) {
        half8_t aF[2], bF[4];
        #pragma unroll
        for (int mi = 0; mi < 2; ++mi)
            aF[mi] = *(const half8_t*)&Q[w * 32 + mi * 16 + lr][kc * 32 + lkg * 8];
        #pragma unroll
        for (int ni = 0; ni < 4; ++ni)
            bF[ni] = *(const half8_t*)&Bv[ni * 16 + lr][kc * 32 + lkg * 8];
        #pragma unroll
        for (int mi = 0; mi < 2; ++mi)
            #pragma unroll
            for (int ni = 0; ni < 4; ++ni)
                acc[mi][ni] = MFMA16(aF[mi], bF[ni], acc[mi][ni]);
    }
    #pragma unroll
    for (int mi = 0; mi < 2; ++mi) {
        #pragma unroll
        for (int ni = 0; ni < 4; ++ni) {
            #pragma unroll
            for (int e = 0; e < 4; ++e) {
                int r = w * 32 + mi * 16 + lkg * 4 + e;
                float v = acc[mi][ni][e] * Z[r];
                q16[(size_t)(row0 + r) * DIM + h * 64 + ni * 16 + lr] = (_Float16)v;
            }
        }
    }
}

// ---------------------------------------------------------------------------
extern "C" void kernel_launch(void* const* d_in, const int* in_sizes, int n_in,
                              void* d_out, int out_size, void* d_ws, size_t ws_size,
                              hipStream_t stream)
{
    const float* xq  = (const float*)d_in[0];  // [8,4096,768]
    const float* xkv = (const float*)d_in[1];  // [8,1024,768]
    const float* Wq  = (const float*)d_in[2];
    const float* Wk  = (const float*)d_in[3];
    const float* Wv  = (const float*)d_in[4];
    const float* Wo  = (const float*)d_in[5];
    const float* bo  = (const float*)d_in[6];

    // ---- workspace layout (~69 MB) ----
    char* ws = (char*)d_ws;
    const size_t SZ_Q16   = (size_t)32768 * 768 * 2;   // 50,331,648
    const size_t SZ_XKV16 = (size_t)8192 * 768 * 2;    // 12,582,912
    const size_t SZ_W16   = (size_t)768 * 768 * 2;     //  1,179,648
    const size_t SZ_KVH   = (size_t)96 * 64 * 64 * 4;  //  1,572,864
    const size_t SZ_KSUM  = (size_t)96 * 64 * 4;       //     24,576

    _Float16* q16   = (_Float16*)(ws);
    _Float16* xkv16 = (_Float16*)(ws + SZ_Q16);
    _Float16* Wq16  = (_Float16*)(ws + SZ_Q16 + SZ_XKV16);            // 4 contiguous
    _Float16* Wk16  = (_Float16*)(ws + SZ_Q16 + SZ_XKV16 + SZ_W16);
    _Float16* Wv16  = (_Float16*)(ws + SZ_Q16 + SZ_XKV16 + 2 * SZ_W16);
    _Float16* Wo16  = (_Float16*)(ws + SZ_Q16 + SZ_XKV16 + 3 * SZ_W16);
    float*    kvh   = (float*)   (ws + SZ_Q16 + SZ_XKV16 + 4 * SZ_W16);
    float*    ksum  = (float*)   (ws + SZ_Q16 + SZ_XKV16 + 4 * SZ_W16 + SZ_KVH);

    // ---- d_out aliasing: xq16 consumed by proj_qkv; k16/v16 by kv_reduce;
    //      all dead before out_proj overwrites d_out. ----
    char* ob = (char*)d_out;
    _Float16* xq16 = (_Float16*)(ob);                       // 50,331,648
    _Float16* k16  = (_Float16*)(ob + 50331648);            // 12,582,912
    _Float16* v16  = (_Float16*)(ob + 50331648 + 12582912); // 12,582,912
    float*    out  = (float*)d_out;

    // 1) one fused cast launch + kv accumulator clear
    cast_all<<<16512, 256, 0, stream>>>(xq, xkv, Wq, Wk, Wv, Wo,
                                        xq16, xkv16, Wq16);
    hipMemsetAsync(kvh, 0, SZ_KVH + SZ_KSUM, stream);

    // 2) fused projections: q = elu1(xq@Wq.T), k = elu1(xkv@Wk.T), v = xkv@Wv.T
    proj_qkv<<<576, 512, 0, stream>>>(xq16, xkv16, Wq16, Wk16, Wv16,
                                      q16, k16, v16);

    // 3) linear attention
    kv_reduce<<<dim3(8, 96), 256, 0, stream>>>(k16, v16, kvh, ksum);
    attn_kernel<<<dim3(12, 256), 256, 0, stream>>>(q16, kvh, ksum);

    // 4) out = attn @ Wo.T + bo  (fp32 output)
    out_proj<<<384, 512, 0, stream>>>(q16, Wo16, bo, out);
}

// Round 9
// 224.373 us; speedup vs baseline: 1.5084x; 1.1887x over previous
//
#include <hip/hip_runtime.h>

typedef _Float16 half8_t __attribute__((ext_vector_type(8)));
typedef _Float16 half4_t __attribute__((ext_vector_type(4)));
typedef float    float4_t __attribute__((ext_vector_type(4)));

#define DIM 768

// async global->LDS, 16B per lane; LDS dest is wave-uniform base + lane*16
#define GLOAD16(g, l) __builtin_amdgcn_global_load_lds(                        \
    (const __attribute__((address_space(1))) void*)(g),                        \
    (__attribute__((address_space(3))) void*)(l), 16, 0, 0)

#define MFMA16(a, b, c) __builtin_amdgcn_mfma_f32_16x16x32_f16((a), (b), (c), 0, 0, 0)

// ---------------------------------------------------------------------------
// one fused cast launch: xq (3,145,728 half8) | xkv (786,432) | weights
// (4 x 73,728; dests contiguous in ws starting at Wq16)
// ---------------------------------------------------------------------------
__global__ __launch_bounds__(256) void cast_all(
    const float* __restrict__ xq,  const float* __restrict__ xkv,
    const float* __restrict__ Wq,  const float* __restrict__ Wk,
    const float* __restrict__ Wv,  const float* __restrict__ Wo,
    _Float16* __restrict__ dq, _Float16* __restrict__ dkv,
    _Float16* __restrict__ dW /* 4 matrices contiguous */)
{
    int i = blockIdx.x * 256 + threadIdx.x;    // grid 16512*256 = 4,227,072
    const float* s; _Float16* d; int off;
    if (i < 3145728)      { s = xq;  d = dq;  off = i; }
    else if (i < 3932160) { s = xkv; d = dkv; off = i - 3145728; }
    else {
        int j = i - 3932160;                   // 0..294911
        int w = j / 73728;  off = j - w * 73728;
        s = (w == 0) ? Wq : (w == 1) ? Wk : (w == 2) ? Wv : Wo;
        d = dW + (size_t)w * 589824;
    }
    float4_t f0 = *(const float4_t*)&s[(size_t)off * 8];
    float4_t f1 = *(const float4_t*)&s[(size_t)off * 8 + 4];
    half8_t h;
    #pragma unroll
    for (int e = 0; e < 4; ++e) { h[e] = (_Float16)f0[e]; h[e + 4] = (_Float16)f1[e]; }
    *(half8_t*)&d[(size_t)off * 8] = h;
}

// ---------------------------------------------------------------------------
// GEMM core — r4's measured-best structure, verbatim (613 TF, 0 conflicts):
// Tile 256x128, BK=64, 512 thr = 8 waves (2M x 4N), per-wave C 128x32.
// 3 LDS slots (48KB each = A 256x64 + B 128x64 fp16, 144KB total).
// Pipeline: compute tile t from slot t%3 while staging tile t+2 into (t+2)%3;
// boundary s_waitcnt vmcnt(6) -- counted, never 0 until the tail (T4).
// 2 phases/tile, 16 MFMA each, setprio around MFMA cluster (T5).
// T2: granule swizzle gphys = glog ^ (row&7) (16B granules), realized as
// inverse-swizzled GLOBAL source + swizzled ds_read (linear LDS dest).
// ---------------------------------------------------------------------------
__device__ __forceinline__ void gemm_core(const _Float16* __restrict__ A,
                                          const _Float16* __restrict__ W,
                                          int row0, int col0,
                                          _Float16* lds, float4_t acc[8][2])
{
    const int tid  = threadIdx.x;
    const int wid  = tid >> 6, lane = tid & 63;
    const int wr   = wid >> 2;            // 0..1 : row half (128 rows)
    const int wc   = wid & 3;             // 0..3 : col quarter (32 cols)
    const int lr   = lane & 15;
    const int lkg  = lane >> 4;           // 0..3
    const int x    = lr & 7;              // swizzle key for reads

    // staging map: call j covers 64 rows; thread -> (row, granule)
    // row = j*64 + wid*8 + (lane>>3); physical granule = lane&7;
    // logical granule = (lane&7) ^ (row&7) = (lane&7) ^ (lane>>3).
    const int  srow = wid * 8 + (lane >> 3);
    const int  sg   = ((lane & 7) ^ (lane >> 3)) * 8;   // halves
    const _Float16* Ast = A + (size_t)(row0 + srow) * DIM + sg;
    const _Float16* Bst = W + (size_t)(col0 + srow) * DIM + sg;

#define LDSA(s) (&lds[(s) * 24576])
#define LDSB(s) (&lds[(s) * 24576 + 16384])
#define STAGE_A(t, s, j) GLOAD16(Ast + (size_t)(t) * 64 + (size_t)(j) * 64 * DIM, \
                                 LDSA(s) + (j) * 4096 + wid * 512)
#define STAGE_B(t, s, j) GLOAD16(Bst + (size_t)(t) * 64 + (size_t)(j) * 64 * DIM, \
                                 LDSB(s) + (j) * 4096 + wid * 512)

    // frag read bases (half indices), swizzled granule per kk
    const int ard = (wr * 128 + lr) * 64;
    const int brd = (wc * 32 + lr) * 64;
    const int g0  = (lkg ^ x) * 8;        // kk = 0
    const int g1  = g0 ^ 32;              // kk = 1 (granule ^ 4)

    // ---- prologue: tile0 -> slot0, tile1 -> slot1 ----
    STAGE_A(0, 0, 0); STAGE_A(0, 0, 1); STAGE_A(0, 0, 2); STAGE_A(0, 0, 3);
    STAGE_B(0, 0, 0); STAGE_B(0, 0, 1);
    STAGE_A(1, 1, 0); STAGE_A(1, 1, 1); STAGE_A(1, 1, 2); STAGE_A(1, 1, 3);
    STAGE_B(1, 1, 0); STAGE_B(1, 1, 1);
    asm volatile("s_waitcnt vmcnt(6)" ::: "memory");   // tile0 landed
    __builtin_amdgcn_s_barrier();

    int s = 0, s2 = 2;
    for (int t = 0; t < 12; ++t) {
        const _Float16* Asl = LDSA(s);
        const _Float16* Bsl = LDSB(s);
        const bool pf = (t < 10);

        // ================= phase 0 : mi 0..3 =================
        half8_t bf[2][2];
        bf[0][0] = *(const half8_t*)&Bsl[brd + g0];
        bf[0][1] = *(const half8_t*)&Bsl[brd + g1];
        bf[1][0] = *(const half8_t*)&Bsl[brd + 1024 + g0];
        bf[1][1] = *(const half8_t*)&Bsl[brd + 1024 + g1];
        half8_t af0[4][2];
        #pragma unroll
        for (int i = 0; i < 4; ++i) {
            af0[i][0] = *(const half8_t*)&Asl[ard + i * 1024 + g0];
            af0[i][1] = *(const half8_t*)&Asl[ard + i * 1024 + g1];
        }
        if (pf) { STAGE_A(t + 2, s2, 0); STAGE_A(t + 2, s2, 1); STAGE_A(t + 2, s2, 2); }
        __builtin_amdgcn_s_barrier();
        asm volatile("s_waitcnt lgkmcnt(0)" ::: "memory");
        __builtin_amdgcn_sched_barrier(0);
        __builtin_amdgcn_s_setprio(1);
        #pragma unroll
        for (int i = 0; i < 4; ++i)
            #pragma unroll
            for (int ni = 0; ni < 2; ++ni) {
                acc[i][ni] = MFMA16(af0[i][0], bf[ni][0], acc[i][ni]);
                acc[i][ni] = MFMA16(af0[i][1], bf[ni][1], acc[i][ni]);
            }
        __builtin_amdgcn_s_setprio(0);
        __builtin_amdgcn_sched_barrier(0);
        __builtin_amdgcn_s_barrier();

        // ================= phase 1 : mi 4..7 =================
        half8_t af1[4][2];
        #pragma unroll
        for (int i = 0; i < 4; ++i) {
            af1[i][0] = *(const half8_t*)&Asl[ard + 4096 + i * 1024 + g0];
            af1[i][1] = *(const half8_t*)&Asl[ard + 4096 + i * 1024 + g1];
        }
        if (pf) { STAGE_A(t + 2, s2, 3); STAGE_B(t + 2, s2, 0); STAGE_B(t + 2, s2, 1); }
        __builtin_amdgcn_s_barrier();
        asm volatile("s_waitcnt lgkmcnt(0)" ::: "memory");
        __builtin_amdgcn_sched_barrier(0);
        __builtin_amdgcn_s_setprio(1);
        #pragma unroll
        for (int i = 0; i < 4; ++i)
            #pragma unroll
            for (int ni = 0; ni < 2; ++ni) {
                acc[4 + i][ni] = MFMA16(af1[i][0], bf[ni][0], acc[4 + i][ni]);
                acc[4 + i][ni] = MFMA16(af1[i][1], bf[ni][1], acc[4 + i][ni]);
            }
        __builtin_amdgcn_s_setprio(0);
        __builtin_amdgcn_sched_barrier(0);

        // ---- tile boundary: counted vmcnt (T4), full drain only at tail ----
        if (t < 11) {
            if (pf) asm volatile("s_waitcnt vmcnt(6)" ::: "memory");
            else    asm volatile("s_waitcnt vmcnt(0)" ::: "memory");
            __builtin_amdgcn_s_barrier();
        }
        s  = (s  == 2) ? 0 : s  + 1;
        s2 = (s2 == 2) ? 0 : s2 + 1;
    }
#undef LDSA
#undef LDSB
#undef STAGE_A
#undef STAGE_B
}

// ---------------------------------------------------------------------------
// Fused q/k/v projection: 1152 blocks (256-row x 128-col tiles).
//   bid <  768 : q = elu1(xq @ Wq.T)   (128 row-blocks x 6)
//   768..959   : k = elu1(xkv @ Wk.T)  ( 32 row-blocks x 6)
//   960..1151  : v =      xkv @ Wv.T
// ---------------------------------------------------------------------------
__global__ __launch_bounds__(512) void proj_qkv(
    const _Float16* __restrict__ xq16, const _Float16* __restrict__ xkv16,
    const _Float16* __restrict__ Wq16, const _Float16* __restrict__ Wk16,
    const _Float16* __restrict__ Wv16,
    _Float16* __restrict__ q16, _Float16* __restrict__ k16,
    _Float16* __restrict__ v16)
{
    __shared__ __align__(16) _Float16 lds[3 * 24576];   // 147456 B

    const int cpx = gridDim.x >> 3;                     // 1152/8 = 144
    int bid = (blockIdx.x & 7) * cpx + (blockIdx.x >> 3);

    const _Float16 *A, *W; _Float16* O; bool elu;
    int brow, bcol;
    if (bid < 768) {
        A = xq16; W = Wq16; O = q16; elu = true;
        brow = bid / 6; bcol = bid - brow * 6;
    } else {
        int u = bid - 768;
        int mat = u / 192;  u -= mat * 192;
        A = xkv16; W = mat ? Wv16 : Wk16; O = mat ? v16 : k16; elu = !mat;
        brow = u / 6; bcol = u - brow * 6;
    }
    const int row0 = brow * 256, col0 = bcol * 128;

    float4_t acc[8][2] = {};
    gemm_core(A, W, row0, col0, lds, acc);

    const int wid = threadIdx.x >> 6, lane = threadIdx.x & 63;
    const int wr = wid >> 2, wc = wid & 3, lr = lane & 15, lkg = lane >> 4;
    #pragma unroll
    for (int mi = 0; mi < 8; ++mi) {
        #pragma unroll
        for (int ni = 0; ni < 2; ++ni) {
            #pragma unroll
            for (int e = 0; e < 4; ++e) {
                int r = row0 + wr * 128 + mi * 16 + lkg * 4 + e;
                int c = col0 + wc * 32 + ni * 16 + lr;
                float v = acc[mi][ni][e];
                if (elu) v = (v > 0.0f) ? (v + 1.0f) : __expf(v);  // elu(x)+1
                O[(size_t)r * DIM + c] = (_Float16)v;
            }
        }
    }
}

// ---------------------------------------------------------------------------
// out = attn16 @ Wo.T + bo  (fp32 output), 768 blocks
// ---------------------------------------------------------------------------
__global__ __launch_bounds__(512) void out_proj(
    const _Float16* __restrict__ a16, const _Float16* __restrict__ Wo16,
    const float* __restrict__ bo, float* __restrict__ out)
{
    __shared__ __align__(16) _Float16 lds[3 * 24576];

    const int cpx = gridDim.x >> 3;                     // 768/8 = 96
    int bid = (blockIdx.x & 7) * cpx + (blockIdx.x >> 3);
    const int brow = bid / 6, bcol = bid - brow * 6;
    const int row0 = brow * 256, col0 = bcol * 128;

    float4_t acc[8][2] = {};
    gemm_core(a16, Wo16, row0, col0, lds, acc);

    const int wid = threadIdx.x >> 6, lane = threadIdx.x & 63;
    const int wr = wid >> 2, wc = wid & 3, lr = lane & 15, lkg = lane >> 4;
    #pragma unroll
    for (int mi = 0; mi < 8; ++mi) {
        #pragma unroll
        for (int ni = 0; ni < 2; ++ni) {
            #pragma unroll
            for (int e = 0; e < 4; ++e) {
                int r = row0 + wr * 128 + mi * 16 + lkg * 4 + e;
                int c = col0 + wc * 32 + ni * 16 + lr;
                out[(size_t)r * DIM + c] = acc[mi][ni][e] + bo[c];
            }
        }
    }
}

// ---------------------------------------------------------------------------
// kv_reduce: per (b,h): kvh[e][d] = sum_n v[n,e]*k[n,d];  ksum[d] = sum_n k[n,d]
// ---------------------------------------------------------------------------
__global__ __launch_bounds__(256) void kv_reduce(const _Float16* __restrict__ k16,
                                                 const _Float16* __restrict__ v16,
                                                 float* __restrict__ kvh,
                                                 float* __restrict__ ksum)
{
    __shared__ __align__(16) _Float16 K[128][64];
    __shared__ __align__(16) _Float16 V[128][64];
    const int chunk = blockIdx.x;   // 0..7
    const int bh    = blockIdx.y;   // 0..95
    const int b = bh / 12, h = bh % 12;
    const int tid = threadIdx.x;

    const size_t base = ((size_t)b * 1024 + (size_t)chunk * 128) * DIM + h * 64;
    #pragma unroll
    for (int j = 0; j < 4; ++j) {
        int idx = j * 256 + tid;
        int r = idx >> 3, c = (idx & 7) * 8;
        *(half8_t*)&K[r][c] = *(const half8_t*)&k16[base + (size_t)r * DIM + c];
        *(half8_t*)&V[r][c] = *(const half8_t*)&v16[base + (size_t)r * DIM + c];
    }
    __syncthreads();

    const int d0 = (tid & 15) * 4;
    const int e0 = (tid >> 4) * 4;
    float acc[4][4] = {};
    #pragma unroll 4
    for (int n = 0; n < 128; ++n) {
        half4_t kd = *(const half4_t*)&K[n][d0];
        half4_t ve = *(const half4_t*)&V[n][e0];
        #pragma unroll
        for (int i = 0; i < 4; ++i)
            #pragma unroll
            for (int j = 0; j < 4; ++j)
                acc[i][j] += (float)ve[i] * (float)kd[j];
    }
    float* kvp = kvh + (size_t)bh * 64 * 64;
    #pragma unroll
    for (int i = 0; i < 4; ++i)
        #pragma unroll
        for (int j = 0; j < 4; ++j)
            atomicAdd(&kvp[(e0 + i) * 64 + d0 + j], acc[i][j]);

    if (tid < 64) {
        float s = 0.0f;
        for (int n = 0; n < 128; ++n) s += (float)K[n][tid];
        atomicAdd(&ksum[bh * 64 + tid], s);
    }
}

// ---------------------------------------------------------------------------
// attn: z = 1/(q . ksum + 1e-6); attn = (q @ kv) * z   (in-place on q16)
// ---------------------------------------------------------------------------
__global__ __launch_bounds__(256) void attn_kernel(_Float16* __restrict__ q16,
                                                   const float* __restrict__ kvh,
                                                   const float* __restrict__ ksum)
{
    __shared__ __align__(16) _Float16 Q[128][72];
    __shared__ __align__(16) _Float16 Bv[64][72];
    __shared__ float S[64];
    __shared__ float Z[128];

    const int h    = blockIdx.x;        // 0..11
    const int rb   = blockIdx.y;        // 0..255
    const int row0 = rb * 128;
    const int b    = row0 >> 12;
    const int bh   = b * 12 + h;
    const int tid  = threadIdx.x;

    #pragma unroll
    for (int j = 0; j < 4; ++j) {
        int idx = j * 256 + tid;
        int r = idx >> 3, c = (idx & 7) * 8;
        *(half8_t*)&Q[r][c] =
            *(const half8_t*)&q16[(size_t)(row0 + r) * DIM + h * 64 + c];
    }
    #pragma unroll
    for (int j = 0; j < 4; ++j) {
        int idx = j * 256 + tid;
        int r = idx >> 4, c = (idx & 15) * 4;
        float4_t f = *(const float4_t*)&kvh[((size_t)bh * 64 + r) * 64 + c];
        half4_t hh;
        #pragma unroll
        for (int e = 0; e < 4; ++e) hh[e] = (_Float16)f[e];
        *(half4_t*)&Bv[r][c] = hh;
    }
    if (tid < 64) S[tid] = ksum[bh * 64 + tid];
    __syncthreads();

    if (tid < 128) {
        float dot = 0.0f;
        #pragma unroll 8
        for (int d = 0; d < 64; ++d) dot += (float)Q[tid][d] * S[d];
        Z[tid] = 1.0f / (dot + 1e-6f);
    }
    __syncthreads();

    const int w = tid >> 6, lane = tid & 63;
    const int lr = lane & 15, lkg = lane >> 4;
    float4_t acc[2][4] = {};
    #pragma unroll
    for (int kc = 0; kc < 2; ++kc) {
        half8_t aF[2], bF[4];
        #pragma unroll
        for (int mi = 0; mi < 2; ++mi)
            aF[mi] = *(const half8_t*)&Q[w * 32 + mi * 16 + lr][kc * 32 + lkg * 8];
        #pragma unroll
        for (int ni = 0; ni < 4; ++ni)
            bF[ni] = *(const half8_t*)&Bv[ni * 16 + lr][kc * 32 + lkg * 8];
        #pragma unroll
        for (int mi = 0; mi < 2; ++mi)
            #pragma unroll
            for (int ni = 0; ni < 4; ++ni)
                acc[mi][ni] = MFMA16(aF[mi], bF[ni], acc[mi][ni]);
    }
    #pragma unroll
    for (int mi = 0; mi < 2; ++mi) {
        #pragma unroll
        for (int ni = 0; ni < 4; ++ni) {
            #pragma unroll
            for (int e = 0; e < 4; ++e) {
                int r = w * 32 + mi * 16 + lkg * 4 + e;
                float v = acc[mi][ni][e] * Z[r];
                q16[(size_t)(row0 + r) * DIM + h * 64 + ni * 16 + lr] = (_Float16)v;
            }
        }
    }
}

// ---------------------------------------------------------------------------
extern "C" void kernel_launch(void* const* d_in, const int* in_sizes, int n_in,
                              void* d_out, int out_size, void* d_ws, size_t ws_size,
                              hipStream_t stream)
{
    const float* xq  = (const float*)d_in[0];  // [8,4096,768]
    const float* xkv = (const float*)d_in[1];  // [8,1024,768]
    const float* Wq  = (const float*)d_in[2];
    const float* Wk  = (const float*)d_in[3];
    const float* Wv  = (const float*)d_in[4];
    const float* Wo  = (const float*)d_in[5];
    const float* bo  = (const float*)d_in[6];

    // ---- workspace layout (~69 MB) ----
    char* ws = (char*)d_ws;
    const size_t SZ_Q16   = (size_t)32768 * 768 * 2;   // 50,331,648
    const size_t SZ_XKV16 = (size_t)8192 * 768 * 2;    // 12,582,912
    const size_t SZ_W16   = (size_t)768 * 768 * 2;     //  1,179,648
    const size_t SZ_KVH   = (size_t)96 * 64 * 64 * 4;  //  1,572,864
    const size_t SZ_KSUM  = (size_t)96 * 64 * 4;       //     24,576

    _Float16* q16   = (_Float16*)(ws);
    _Float16* xkv16 = (_Float16*)(ws + SZ_Q16);
    _Float16* Wq16  = (_Float16*)(ws + SZ_Q16 + SZ_XKV16);            // 4 contiguous
    _Float16* Wk16  = (_Float16*)(ws + SZ_Q16 + SZ_XKV16 + SZ_W16);
    _Float16* Wv16  = (_Float16*)(ws + SZ_Q16 + SZ_XKV16 + 2 * SZ_W16);
    _Float16* Wo16  = (_Float16*)(ws + SZ_Q16 + SZ_XKV16 + 3 * SZ_W16);
    float*    kvh   = (float*)   (ws + SZ_Q16 + SZ_XKV16 + 4 * SZ_W16);
    float*    ksum  = (float*)   (ws + SZ_Q16 + SZ_XKV16 + 4 * SZ_W16 + SZ_KVH);

    // ---- d_out aliasing: xq16 consumed by proj_qkv; k16/v16 by kv_reduce;
    //      all dead before out_proj overwrites d_out. ----
    char* ob = (char*)d_out;
    _Float16* xq16 = (_Float16*)(ob);                       // 50,331,648
    _Float16* k16  = (_Float16*)(ob + 50331648);            // 12,582,912
    _Float16* v16  = (_Float16*)(ob + 50331648 + 12582912); // 12,582,912
    float*    out  = (float*)d_out;

    // 1) one fused cast launch + kv accumulator clear
    cast_all<<<16512, 256, 0, stream>>>(xq, xkv, Wq, Wk, Wv, Wo,
                                        xq16, xkv16, Wq16);
    hipMemsetAsync(kvh, 0, SZ_KVH + SZ_KSUM, stream);

    // 2) fused projections: q = elu1(xq@Wq.T), k = elu1(xkv@Wk.T), v = xkv@Wv.T
    proj_qkv<<<1152, 512, 0, stream>>>(xq16, xkv16, Wq16, Wk16, Wv16,
                                       q16, k16, v16);

    // 3) linear attention
    kv_reduce<<<dim3(8, 96), 256, 0, stream>>>(k16, v16, kvh, ksum);
    attn_kernel<<<dim3(12, 256), 256, 0, stream>>>(q16, kvh, ksum);

    // 4) out = attn @ Wo.T + bo  (fp32 output)
    out_proj<<<768, 512, 0, stream>>>(q16, Wo16, bo, out);
}